// Round 12
// baseline (643.629 us; speedup 1.0000x reference)
//
#include <hip/hip_runtime.h>
#include <math.h>

#define NFEAT 128
#define INF   64
#define BN_RSQ 0.99999500003749937f

// ---------------------------------------------------------------------------
// linear8: out[n,128] = in[n,K] @ W[K,128] (+bias). 64x128 block tile
// (grid ~782 -> ~3 blocks/CU), 4x8 microtile per thread, rows/cols strided
// by 16 so LDS reads are conflict-free ds_read_b128 with the 36-float stride.
// ---------------------------------------------------------------------------
template <int K>
__launch_bounds__(256)
__global__ void linear8_kernel(const float* __restrict__ in, const float* __restrict__ W,
                               const float* __restrict__ bias, float* __restrict__ out, int n) {
    __shared__ float xs[64 * 36];    // [row][k] padded stride 36 floats
    __shared__ float wt[128 * 36];   // [col][k] transposed, same padding
    const int tid = threadIdx.x;
    const int tx = tid & 15;         // col group
    const int ty = tid >> 4;         // row group
    const int row0 = blockIdx.x * 64;
    float acc[4][8] = {};
    for (int kc = 0; kc < K; kc += 32) {
        __syncthreads();
        // stage x: 64 rows x 32 ks (2 float4 per thread)
#pragma unroll
        for (int r = 0; r < 2; ++r) {
            const int idx = tid + 256 * r;
            const int rr = idx >> 3;
            const int k4 = (idx & 7) << 2;
            const int row = row0 + rr;
            float4 v = make_float4(0.f, 0.f, 0.f, 0.f);
            if (row < n) v = *(const float4*)&in[(long)row * K + kc + k4];
            *(float4*)&xs[rr * 36 + k4] = v;
        }
        // stage W transposed: 32 ks x 128 cols (4 float4 per thread)
#pragma unroll
        for (int r = 0; r < 4; ++r) {
            const int idx = tid + 256 * r;
            const int kk = idx >> 5;
            const int c4 = (idx & 31) << 2;
            const float4 v = *(const float4*)&W[(long)(kc + kk) * 128 + c4];
            wt[(c4 + 0) * 36 + kk] = v.x;
            wt[(c4 + 1) * 36 + kk] = v.y;
            wt[(c4 + 2) * 36 + kk] = v.z;
            wt[(c4 + 3) * 36 + kk] = v.w;
        }
        __syncthreads();
#pragma unroll 2
        for (int k4 = 0; k4 < 32; k4 += 4) {
            float4 xa[4], wa[8];
#pragma unroll
            for (int i = 0; i < 4; ++i) xa[i] = *(const float4*)&xs[(ty + 16 * i) * 36 + k4];
#pragma unroll
            for (int j = 0; j < 8; ++j) wa[j] = *(const float4*)&wt[(tx + 16 * j) * 36 + k4];
#pragma unroll
            for (int i = 0; i < 4; ++i)
#pragma unroll
                for (int j = 0; j < 8; ++j) {
                    acc[i][j] = fmaf(xa[i].x, wa[j].x, acc[i][j]);
                    acc[i][j] = fmaf(xa[i].y, wa[j].y, acc[i][j]);
                    acc[i][j] = fmaf(xa[i].z, wa[j].z, acc[i][j]);
                    acc[i][j] = fmaf(xa[i].w, wa[j].w, acc[i][j]);
                }
        }
    }
#pragma unroll
    for (int i = 0; i < 4; ++i) {
        const int row = row0 + ty + 16 * i;
        if (row >= n) continue;
#pragma unroll
        for (int j = 0; j < 8; ++j) {
            const int col = tx + 16 * j;
            float v = acc[i][j];
            if (bias) v += bias[col];
            out[(long)row * 128 + col] = v;
        }
    }
}

// ---------------------------------------------------------------------------
// linear4 (Wc1): 64x64 tile, 4x4 microtile. EPI 2 = relu then BN.
// ---------------------------------------------------------------------------
template <int K, int NT, int EPI>
__launch_bounds__(256)
__global__ void linear4_kernel(const float* __restrict__ in, const float* __restrict__ W,
                               const float* __restrict__ bias, const float* __restrict__ g,
                               const float* __restrict__ be, float* __restrict__ out, int n) {
    __shared__ float xs[64 * 68];
    __shared__ float wsm[64 * 68];
    const int tx = threadIdx.x & 15;
    const int ty = threadIdx.x >> 4;
    const int row0 = blockIdx.x * 64;
    const int col0 = blockIdx.y * 64;
    float acc[4][4] = {};
    for (int kc = 0; kc < K; kc += 64) {
        __syncthreads();
        for (int i = threadIdx.x; i < 1024; i += 256) {
            const int rr = i >> 4;
            const int k4 = (i & 15) << 2;
            const int row = row0 + rr;
            float4 v = make_float4(0.f, 0.f, 0.f, 0.f);
            if (row < n) v = *(const float4*)&in[(long)row * K + kc + k4];
            *(float4*)&xs[rr * 68 + k4] = v;
        }
        for (int i = threadIdx.x; i < 1024; i += 256) {
            const int kk = i >> 4;
            const int j4 = (i & 15) << 2;
            *(float4*)&wsm[kk * 68 + j4] =
                *(const float4*)&W[(long)(kc + kk) * NT + col0 + j4];
        }
        __syncthreads();
#pragma unroll 16
        for (int k = 0; k < 64; ++k) {
            const float4 wv = *(const float4*)&wsm[k * 68 + (tx << 2)];
            const float x0 = xs[(ty * 4 + 0) * 68 + k];
            const float x1 = xs[(ty * 4 + 1) * 68 + k];
            const float x2 = xs[(ty * 4 + 2) * 68 + k];
            const float x3 = xs[(ty * 4 + 3) * 68 + k];
            acc[0][0] = fmaf(x0, wv.x, acc[0][0]); acc[0][1] = fmaf(x0, wv.y, acc[0][1]);
            acc[0][2] = fmaf(x0, wv.z, acc[0][2]); acc[0][3] = fmaf(x0, wv.w, acc[0][3]);
            acc[1][0] = fmaf(x1, wv.x, acc[1][0]); acc[1][1] = fmaf(x1, wv.y, acc[1][1]);
            acc[1][2] = fmaf(x1, wv.z, acc[1][2]); acc[1][3] = fmaf(x1, wv.w, acc[1][3]);
            acc[2][0] = fmaf(x2, wv.x, acc[2][0]); acc[2][1] = fmaf(x2, wv.y, acc[2][1]);
            acc[2][2] = fmaf(x2, wv.z, acc[2][2]); acc[2][3] = fmaf(x2, wv.w, acc[2][3]);
            acc[3][0] = fmaf(x3, wv.x, acc[3][0]); acc[3][1] = fmaf(x3, wv.y, acc[3][1]);
            acc[3][2] = fmaf(x3, wv.z, acc[3][2]); acc[3][3] = fmaf(x3, wv.w, acc[3][3]);
        }
    }
    const int col = col0 + (tx << 2);
    float4 bv = make_float4(0.f, 0.f, 0.f, 0.f);
    if (bias) bv = *(const float4*)&bias[col];
    float4 gv, ev;
    if (EPI == 2) { gv = *(const float4*)&g[col]; ev = *(const float4*)&be[col]; }
#pragma unroll
    for (int i = 0; i < 4; ++i) {
        const int row = row0 + ty * 4 + i;
        if (row >= n) break;
        float4 v = make_float4(acc[i][0] + bv.x, acc[i][1] + bv.y,
                               acc[i][2] + bv.z, acc[i][3] + bv.w);
        if (EPI == 2) {
            v.x = fmaxf(v.x, 0.f) * (gv.x * BN_RSQ) + ev.x;
            v.y = fmaxf(v.y, 0.f) * (gv.y * BN_RSQ) + ev.y;
            v.z = fmaxf(v.z, 0.f) * (gv.z * BN_RSQ) + ev.z;
            v.w = fmaxf(v.w, 0.f) * (gv.w * BN_RSQ) + ev.w;
        }
        *(float4*)&out[(long)row * NT + col] = v;
    }
}

// ---------------------------------------------------------------------------
// Small linear (classifier tails)
// ---------------------------------------------------------------------------
template <int K, int MT, int MFULL, int EPI, int ITERS>
__launch_bounds__(256)
__global__ void linear_kernel(const float* __restrict__ in, const float* __restrict__ W,
                              const float* __restrict__ bias, float* __restrict__ out, int n) {
    constexpr int RPI = 256 / MT;
    __shared__ float Wl[K * MT];
    __shared__ float xl[RPI * (K + 1)];
    for (int i = threadIdx.x; i < K * MT; i += 256)
        Wl[i] = W[(i / MT) * MFULL + (i % MT)];
    const int j = threadIdx.x % MT;
    const int r = threadIdx.x / MT;
    const int row0 = blockIdx.x * (RPI * ITERS);
    for (int it = 0; it < ITERS; ++it) {
        const int base = row0 + it * RPI;
        __syncthreads();
        for (int i = threadIdx.x; i < RPI * K; i += 256) {
            int rr = i / K, kk = i - rr * K;
            int row = base + rr;
            xl[rr * (K + 1) + kk] = (row < n) ? in[(long)row * K + kk] : 0.f;
        }
        __syncthreads();
        float acc = 0.f;
#pragma unroll
        for (int k = 0; k < K; ++k) acc += xl[r * (K + 1) + k] * Wl[k * MT + j];
        const int row = base + r;
        if (row < n) {
            float v = acc;
            if (bias) v += bias[j];
            if (EPI >= 1) v = fmaxf(v, 0.f);
            out[(long)row * MFULL + j] = v;
        }
    }
}

// ---------------------------------------------------------------------------
// Per-node attention logits (float4 inner loop)
// ---------------------------------------------------------------------------
template <int H, int C>
__global__ void gat_logits_kernel(const float* __restrict__ xh, const float* __restrict__ a_s,
                                  const float* __restrict__ a_d, float* __restrict__ als,
                                  float* __restrict__ ald, int n) {
    int idx = blockIdx.x * blockDim.x + threadIdx.x;
    if (idx >= n * H) return;
    int node = idx / H, h = idx - node * H;
    const float4* xp  = (const float4*)(xh + (long)node * NFEAT + h * C);
    const float4* asp = (const float4*)(a_s + h * C);
    const float4* adp = (const float4*)(a_d + h * C);
    float ss = 0.f, sd = 0.f;
#pragma unroll
    for (int c = 0; c < C / 4; ++c) {
        float4 v = xp[c], a = asp[c], b = adp[c];
        ss += v.x * a.x + v.y * a.y + v.z * a.z + v.w * a.w;
        sd += v.x * b.x + v.y * b.y + v.z * b.z + v.w * b.w;
    }
    als[idx] = ss;
    ald[idx] = sd;
}

// ---------------------------------------------------------------------------
// CSR build
// ---------------------------------------------------------------------------
__global__ void zero_int_kernel(int* __restrict__ p, int n) {
    int i = blockIdx.x * blockDim.x + threadIdx.x;
    if (i < n) p[i] = 0;
}

__global__ void hist_kernel(const int* __restrict__ ei, int E, int n, int* __restrict__ deg) {
    int e = blockIdx.x * blockDim.x + threadIdx.x;
    if (e >= E + n) return;
    int d = (e < E) ? ei[E + e] : (e - E);
    atomicAdd(&deg[d], 1);
}

__global__ void scanA_kernel(const int* __restrict__ deg, int n,
                             int* __restrict__ rowptr, int* __restrict__ bsum) {
    __shared__ int s[256];
    int t = threadIdx.x;
    int idx = blockIdx.x * 256 + t;
    s[t] = (idx < n) ? deg[idx] : 0;
    __syncthreads();
    for (int o = 1; o < 256; o <<= 1) {
        int x = (t >= o) ? s[t - o] : 0;
        __syncthreads();
        s[t] += x;
        __syncthreads();
    }
    if (idx < n) rowptr[idx + 1] = s[t];
    if (t == 255) bsum[blockIdx.x] = s[255];
}

__global__ void scanB_kernel(int* __restrict__ bsum, int nb) {
    __shared__ int s[256];
    int t = threadIdx.x;
    s[t] = (t < nb) ? bsum[t] : 0;
    __syncthreads();
    for (int o = 1; o < 256; o <<= 1) {
        int x = (t >= o) ? s[t - o] : 0;
        __syncthreads();
        s[t] += x;
        __syncthreads();
    }
    if (t < nb) bsum[t] = s[t];
}

__global__ void scanC_kernel(const int* __restrict__ deg, int n, int* __restrict__ rowptr,
                             const int* __restrict__ bsum, int* __restrict__ cursor) {
    int idx = blockIdx.x * 256 + threadIdx.x;
    if (idx >= n) return;
    int off = (blockIdx.x > 0) ? bsum[blockIdx.x - 1] : 0;
    int val = rowptr[idx + 1] + off;
    rowptr[idx + 1] = val;
    cursor[idx] = val - deg[idx];
    if (idx == 0) rowptr[0] = 0;
}

__global__ void scatter_kernel(const int* __restrict__ ei, int E, int n,
                               int* __restrict__ cursor, int* __restrict__ csr_src) {
    int e = blockIdx.x * blockDim.x + threadIdx.x;
    if (e >= E + n) return;
    int s, d;
    if (e < E) { s = ei[e]; d = ei[E + e]; } else { s = e - E; d = s; }
    int pos = atomicAdd(&cursor[d], 1);
    csr_src[pos] = s;
}

// ---------------------------------------------------------------------------
// Fused gather v3: lane covers features {2*lane, 2*lane+1} -> ONE
// global_load_dwordx2 per edge per lane (same 512B/wave coalesced footprint,
// half the VMEM instructions of v2) and both features share one head
// (head = lane>>4 for H=4) -> one LDS weight read + one den accumulator.
// Batch phase computes per-edge head weights into LDS; t-loop unrolled x4
// for 4 independent loads in flight. No max-subtraction (the max cancels
// exactly in the softmax ratio; logits are exp-safe).
// ---------------------------------------------------------------------------
template <int H>
__launch_bounds__(256)
__global__ void gat_gather_kernel(const int* __restrict__ rowptr, const int* __restrict__ csr_src,
                                  const float* __restrict__ xh, const float* __restrict__ als,
                                  const float* __restrict__ ald, const float* __restrict__ bias,
                                  const float* __restrict__ g, const float* __restrict__ be,
                                  const float* __restrict__ post, float* __restrict__ hout, int n) {
    __shared__ int   slds[4][64];
    __shared__ float wlds[4][64][H];
    const int lane = threadIdx.x & 63;
    const int wid  = threadIdx.x >> 6;
    const int d = blockIdx.x * 4 + wid;
    if (d >= n) return;
    const int c0 = lane << 1;                       // features c0, c0+1 (same head)
    const int hh = (H == 4) ? (lane >> 4) : 0;
    float4 adv;
    if (H == 4) adv = *(const float4*)&ald[d * 4];
    else        adv.x = ald[d];
    const int rs = rowptr[d], re = rowptr[d + 1];   // deg >= 1 (self-loop)
    float den = 0.f, acc0 = 0.f, acc1 = 0.f;
    for (int base = rs; base < re; base += 64) {
        // ---- batch phase: lane's own edge -> head weights into LDS ----
        const bool valid = (base + lane) < re;
        int sv = 0;
        if (valid) sv = csr_src[base + lane];
        if (H == 4) {
            const float4 a = *(const float4*)&als[sv * 4];
            float l0 = a.x + adv.x, l1 = a.y + adv.y, l2 = a.z + adv.z, l3 = a.w + adv.w;
            l0 = l0 > 0.f ? l0 : 0.2f * l0;
            l1 = l1 > 0.f ? l1 : 0.2f * l1;
            l2 = l2 > 0.f ? l2 : 0.2f * l2;
            l3 = l3 > 0.f ? l3 : 0.2f * l3;
            float4 wv;
            wv.x = valid ? __expf(l0) : 0.f;
            wv.y = valid ? __expf(l1) : 0.f;
            wv.z = valid ? __expf(l2) : 0.f;
            wv.w = valid ? __expf(l3) : 0.f;
            slds[wid][lane] = sv;
            *(float4*)&wlds[wid][lane][0] = wv;
        } else {
            float l = als[sv] + adv.x;
            l = l > 0.f ? l : 0.2f * l;
            slds[wid][lane] = sv;
            wlds[wid][lane][0] = valid ? __expf(l) : 0.f;
        }
        const int cnt = min(64, re - base);
        const int cnt4 = (cnt + 3) & ~3;            // pad slots carry w=0, sv=0
        for (int t = 0; t < cnt4; t += 4) {
            const int s0 = slds[wid][t + 0];
            const int s1 = slds[wid][t + 1];
            const int s2 = slds[wid][t + 2];
            const int s3 = slds[wid][t + 3];
            const float w0 = wlds[wid][t + 0][hh];
            const float w1 = wlds[wid][t + 1][hh];
            const float w2 = wlds[wid][t + 2][hh];
            const float w3 = wlds[wid][t + 3][hh];
            const float2 x0 = *(const float2*)&xh[(long)s0 * NFEAT + c0];
            const float2 x1 = *(const float2*)&xh[(long)s1 * NFEAT + c0];
            const float2 x2 = *(const float2*)&xh[(long)s2 * NFEAT + c0];
            const float2 x3 = *(const float2*)&xh[(long)s3 * NFEAT + c0];
            den += (w0 + w1) + (w2 + w3);
            acc0 = fmaf(w0, x0.x, acc0); acc1 = fmaf(w0, x0.y, acc1);
            acc0 = fmaf(w1, x1.x, acc0); acc1 = fmaf(w1, x1.y, acc1);
            acc0 = fmaf(w2, x2.x, acc0); acc1 = fmaf(w2, x2.y, acc1);
            acc0 = fmaf(w3, x3.x, acc0); acc1 = fmaf(w3, x3.y, acc1);
        }
    }
    const float2 bv = *(const float2*)&bias[c0];
    const float2 gv = *(const float2*)&g[c0];
    const float2 ev = *(const float2*)&be[c0];
    const float rden = 1.f / den;
    float v0 = (acc0 * rden + bv.x) * (gv.x * BN_RSQ) + ev.x;
    float v1 = (acc1 * rden + bv.y) * (gv.y * BN_RSQ) + ev.y;
    v0 = v0 > 0.f ? v0 : expm1f(v0);                // elu
    v1 = v1 > 0.f ? v1 : expm1f(v1);
    if (post) { const float2 pv = *(const float2*)&post[c0]; v0 *= pv.x; v1 *= pv.y; }
    float2 o; o.x = v0; o.y = v1;
    *(float2*)&hout[(long)d * NFEAT + c0] = o;
}

// ---------------------------------------------------------------------------
template <int H>
static void run_gat_layer(const float* hin, float* xh, float* als, float* ald,
                          const int* rowptr, const int* csr_src, int n,
                          const float* W, const float* as_, const float* ad_, const float* b,
                          const float* g, const float* be, const float* post, float* hout,
                          hipStream_t stream) {
    constexpr int C = NFEAT / H;
    linear8_kernel<128><<<(n + 63) / 64, 256, 0, stream>>>(hin, W, nullptr, xh, n);
    gat_logits_kernel<H, C><<<(n * H + 255) / 256, 256, 0, stream>>>(xh, as_, ad_, als, ald, n);
    gat_gather_kernel<H><<<(n + 3) / 4, 256, 0, stream>>>(rowptr, csr_src, xh, als, ald,
                                                          b, g, be, post, hout, n);
}

extern "C" void kernel_launch(void* const* d_in, const int* in_sizes, int n_in,
                              void* d_out, int out_size, void* d_ws, size_t ws_size,
                              hipStream_t stream) {
    const float* x   = (const float*)d_in[0];
    const int*   ei  = (const int*)d_in[1];
    const float* Wp  = (const float*)d_in[2];
    const float* bp  = (const float*)d_in[3];
    const float* W0  = (const float*)d_in[4];
    const float* as0 = (const float*)d_in[5];
    const float* ad0 = (const float*)d_in[6];
    const float* b0  = (const float*)d_in[7];
    const float* g0  = (const float*)d_in[8];
    const float* be0 = (const float*)d_in[9];
    const float* W1  = (const float*)d_in[10];
    const float* as1 = (const float*)d_in[11];
    const float* ad1 = (const float*)d_in[12];
    const float* b1  = (const float*)d_in[13];
    const float* g1  = (const float*)d_in[14];
    const float* be1 = (const float*)d_in[15];
    const float* W2  = (const float*)d_in[16];
    const float* as2 = (const float*)d_in[17];
    const float* ad2 = (const float*)d_in[18];
    const float* b2  = (const float*)d_in[19];
    const float* g2  = (const float*)d_in[20];
    const float* be2 = (const float*)d_in[21];
    const float* fi  = (const float*)d_in[22];
    const float* Wc1 = (const float*)d_in[23];
    const float* bc1 = (const float*)d_in[24];
    const float* gc  = (const float*)d_in[25];
    const float* bec = (const float*)d_in[26];
    const float* Wc2 = (const float*)d_in[27];
    const float* bc2 = (const float*)d_in[28];
    const float* Wc3 = (const float*)d_in[29];
    const float* bc3 = (const float*)d_in[30];

    const int n  = in_sizes[0] / INF;      // 50000
    const int E  = in_sizes[1] / 2;        // 800000
    const int E2 = E + n;                  // + self-loops
    const int NB = (n + 255) / 256;        // scan blocks (<=256)

    float* ws   = (float*)d_ws;
    float* h    = ws;                          // n*128
    float* xh   = h + (long)n * NFEAT;         // n*128
    float* als  = xh + (long)n * NFEAT;        // n*4
    float* ald  = als + (long)n * 4;           // n*4
    int* deg     = (int*)(ald + (long)n * 4);  // n
    int* rowptr  = deg + n;                    // n+1
    int* cursor  = rowptr + (n + 1);           // n
    int* csr_src = cursor + n;                 // E2
    int* bsum    = csr_src + (long)E2;         // NB

    // CSR build (by dst)
    zero_int_kernel<<<NB, 256, 0, stream>>>(deg, n);
    hist_kernel<<<(E2 + 255) / 256, 256, 0, stream>>>(ei, E, n, deg);
    scanA_kernel<<<NB, 256, 0, stream>>>(deg, n, rowptr, bsum);
    scanB_kernel<<<1, 256, 0, stream>>>(bsum, NB);
    scanC_kernel<<<NB, 256, 0, stream>>>(deg, n, rowptr, bsum, cursor);
    scatter_kernel<<<(E2 + 255) / 256, 256, 0, stream>>>(ei, E, n, cursor, csr_src);

    // projection: h = x @ Wp + bp
    linear8_kernel<64><<<(n + 63) / 64, 256, 0, stream>>>(x, Wp, bp, h, n);

    // GAT layers (h -> h across kernels; stream-ordered)
    run_gat_layer<4>(h, xh, als, ald, rowptr, csr_src, n, W0, as0, ad0, b0, g0, be0, nullptr, h, stream);
    run_gat_layer<4>(h, xh, als, ald, rowptr, csr_src, n, W1, as1, ad1, b1, g1, be1, nullptr, h, stream);
    run_gat_layer<1>(h, xh, als, ald, rowptr, csr_src, n, W2, as2, ad2, b2, g2, be2, fi, h, stream);

    // classifier: c1 = bn(relu(h@Wc1+bc1)) -> xh ; c2 = relu(c1@Wc2+bc2) -> h ; out
    {
        dim3 grid((n + 63) / 64, 1);
        linear4_kernel<128, 64, 2><<<grid, 256, 0, stream>>>(h, Wc1, bc1, gc, bec, xh, n);
    }
    linear_kernel<64, 32, 32, 1, 8><<<(n + 63) / 64, 256, 0, stream>>>(xh, Wc2, bc2, h, n);
    linear_kernel<32, 2, 2, 0, 2><<<(n + 255) / 256, 256, 0, stream>>>(h, Wc3, bc3, (float*)d_out, n);
}

// Round 13
// 563.663 us; speedup vs baseline: 1.1419x; 1.1419x over previous
//
#include <hip/hip_runtime.h>
#include <hip/hip_fp16.h>
#include <math.h>

#define NFEAT 128
#define INF   64
#define BN_RSQ 0.99999500003749937f

// ---------------------------------------------------------------------------
// linear8: out[n,128] = in[n,K] @ W[K,128] (+bias). 64x128 block tile,
// 4x8 microtile, conflict-free ds_read_b128 via 36-float padded stride.
// OBF=1: write fp16 (ushort) output instead of fp32 (halves write traffic;
// feeds the fp16 gather path).
// ---------------------------------------------------------------------------
template <int K, int OBF>
__launch_bounds__(256)
__global__ void linear8_kernel(const float* __restrict__ in, const float* __restrict__ W,
                               const float* __restrict__ bias, void* __restrict__ outv, int n) {
    __shared__ float xs[64 * 36];    // [row][k] padded stride 36 floats
    __shared__ float wt[128 * 36];   // [col][k] transposed, same padding
    const int tid = threadIdx.x;
    const int tx = tid & 15;         // col group
    const int ty = tid >> 4;         // row group
    const int row0 = blockIdx.x * 64;
    float acc[4][8] = {};
    for (int kc = 0; kc < K; kc += 32) {
        __syncthreads();
        // stage x: 64 rows x 32 ks (2 float4 per thread)
#pragma unroll
        for (int r = 0; r < 2; ++r) {
            const int idx = tid + 256 * r;
            const int rr = idx >> 3;
            const int k4 = (idx & 7) << 2;
            const int row = row0 + rr;
            float4 v = make_float4(0.f, 0.f, 0.f, 0.f);
            if (row < n) v = *(const float4*)&in[(long)row * K + kc + k4];
            *(float4*)&xs[rr * 36 + k4] = v;
        }
        // stage W transposed: 32 ks x 128 cols (4 float4 per thread)
#pragma unroll
        for (int r = 0; r < 4; ++r) {
            const int idx = tid + 256 * r;
            const int kk = idx >> 5;
            const int c4 = (idx & 31) << 2;
            const float4 v = *(const float4*)&W[(long)(kc + kk) * 128 + c4];
            wt[(c4 + 0) * 36 + kk] = v.x;
            wt[(c4 + 1) * 36 + kk] = v.y;
            wt[(c4 + 2) * 36 + kk] = v.z;
            wt[(c4 + 3) * 36 + kk] = v.w;
        }
        __syncthreads();
#pragma unroll 2
        for (int k4 = 0; k4 < 32; k4 += 4) {
            float4 xa[4], wa[8];
#pragma unroll
            for (int i = 0; i < 4; ++i) xa[i] = *(const float4*)&xs[(ty + 16 * i) * 36 + k4];
#pragma unroll
            for (int j = 0; j < 8; ++j) wa[j] = *(const float4*)&wt[(tx + 16 * j) * 36 + k4];
#pragma unroll
            for (int i = 0; i < 4; ++i)
#pragma unroll
                for (int j = 0; j < 8; ++j) {
                    acc[i][j] = fmaf(xa[i].x, wa[j].x, acc[i][j]);
                    acc[i][j] = fmaf(xa[i].y, wa[j].y, acc[i][j]);
                    acc[i][j] = fmaf(xa[i].z, wa[j].z, acc[i][j]);
                    acc[i][j] = fmaf(xa[i].w, wa[j].w, acc[i][j]);
                }
        }
    }
#pragma unroll
    for (int i = 0; i < 4; ++i) {
        const int row = row0 + ty + 16 * i;
        if (row >= n) continue;
#pragma unroll
        for (int j = 0; j < 8; ++j) {
            const int col = tx + 16 * j;
            float v = acc[i][j];
            if (bias) v += bias[col];
            if (OBF) ((__half*)outv)[(long)row * 128 + col] = __float2half(v);
            else     ((float*)outv)[(long)row * 128 + col] = v;
        }
    }
}

// ---------------------------------------------------------------------------
// linear4 (Wc1): 64x64 tile, 4x4 microtile. EPI 2 = relu then BN.
// ---------------------------------------------------------------------------
template <int K, int NT, int EPI>
__launch_bounds__(256)
__global__ void linear4_kernel(const float* __restrict__ in, const float* __restrict__ W,
                               const float* __restrict__ bias, const float* __restrict__ g,
                               const float* __restrict__ be, float* __restrict__ out, int n) {
    __shared__ float xs[64 * 68];
    __shared__ float wsm[64 * 68];
    const int tx = threadIdx.x & 15;
    const int ty = threadIdx.x >> 4;
    const int row0 = blockIdx.x * 64;
    const int col0 = blockIdx.y * 64;
    float acc[4][4] = {};
    for (int kc = 0; kc < K; kc += 64) {
        __syncthreads();
        for (int i = threadIdx.x; i < 1024; i += 256) {
            const int rr = i >> 4;
            const int k4 = (i & 15) << 2;
            const int row = row0 + rr;
            float4 v = make_float4(0.f, 0.f, 0.f, 0.f);
            if (row < n) v = *(const float4*)&in[(long)row * K + kc + k4];
            *(float4*)&xs[rr * 68 + k4] = v;
        }
        for (int i = threadIdx.x; i < 1024; i += 256) {
            const int kk = i >> 4;
            const int j4 = (i & 15) << 2;
            *(float4*)&wsm[kk * 68 + j4] =
                *(const float4*)&W[(long)(kc + kk) * NT + col0 + j4];
        }
        __syncthreads();
#pragma unroll 16
        for (int k = 0; k < 64; ++k) {
            const float4 wv = *(const float4*)&wsm[k * 68 + (tx << 2)];
            const float x0 = xs[(ty * 4 + 0) * 68 + k];
            const float x1 = xs[(ty * 4 + 1) * 68 + k];
            const float x2 = xs[(ty * 4 + 2) * 68 + k];
            const float x3 = xs[(ty * 4 + 3) * 68 + k];
            acc[0][0] = fmaf(x0, wv.x, acc[0][0]); acc[0][1] = fmaf(x0, wv.y, acc[0][1]);
            acc[0][2] = fmaf(x0, wv.z, acc[0][2]); acc[0][3] = fmaf(x0, wv.w, acc[0][3]);
            acc[1][0] = fmaf(x1, wv.x, acc[1][0]); acc[1][1] = fmaf(x1, wv.y, acc[1][1]);
            acc[1][2] = fmaf(x1, wv.z, acc[1][2]); acc[1][3] = fmaf(x1, wv.w, acc[1][3]);
            acc[2][0] = fmaf(x2, wv.x, acc[2][0]); acc[2][1] = fmaf(x2, wv.y, acc[2][1]);
            acc[2][2] = fmaf(x2, wv.z, acc[2][2]); acc[2][3] = fmaf(x2, wv.w, acc[2][3]);
            acc[3][0] = fmaf(x3, wv.x, acc[3][0]); acc[3][1] = fmaf(x3, wv.y, acc[3][1]);
            acc[3][2] = fmaf(x3, wv.z, acc[3][2]); acc[3][3] = fmaf(x3, wv.w, acc[3][3]);
        }
    }
    const int col = col0 + (tx << 2);
    float4 bv = make_float4(0.f, 0.f, 0.f, 0.f);
    if (bias) bv = *(const float4*)&bias[col];
    float4 gv, ev;
    if (EPI == 2) { gv = *(const float4*)&g[col]; ev = *(const float4*)&be[col]; }
#pragma unroll
    for (int i = 0; i < 4; ++i) {
        const int row = row0 + ty * 4 + i;
        if (row >= n) break;
        float4 v = make_float4(acc[i][0] + bv.x, acc[i][1] + bv.y,
                               acc[i][2] + bv.z, acc[i][3] + bv.w);
        if (EPI == 2) {
            v.x = fmaxf(v.x, 0.f) * (gv.x * BN_RSQ) + ev.x;
            v.y = fmaxf(v.y, 0.f) * (gv.y * BN_RSQ) + ev.y;
            v.z = fmaxf(v.z, 0.f) * (gv.z * BN_RSQ) + ev.z;
            v.w = fmaxf(v.w, 0.f) * (gv.w * BN_RSQ) + ev.w;
        }
        *(float4*)&out[(long)row * NT + col] = v;
    }
}

// ---------------------------------------------------------------------------
// Small linear (classifier tails)
// ---------------------------------------------------------------------------
template <int K, int MT, int MFULL, int EPI, int ITERS>
__launch_bounds__(256)
__global__ void linear_kernel(const float* __restrict__ in, const float* __restrict__ W,
                              const float* __restrict__ bias, float* __restrict__ out, int n) {
    constexpr int RPI = 256 / MT;
    __shared__ float Wl[K * MT];
    __shared__ float xl[RPI * (K + 1)];
    for (int i = threadIdx.x; i < K * MT; i += 256)
        Wl[i] = W[(i / MT) * MFULL + (i % MT)];
    const int j = threadIdx.x % MT;
    const int r = threadIdx.x / MT;
    const int row0 = blockIdx.x * (RPI * ITERS);
    for (int it = 0; it < ITERS; ++it) {
        const int base = row0 + it * RPI;
        __syncthreads();
        for (int i = threadIdx.x; i < RPI * K; i += 256) {
            int rr = i / K, kk = i - rr * K;
            int row = base + rr;
            xl[rr * (K + 1) + kk] = (row < n) ? in[(long)row * K + kk] : 0.f;
        }
        __syncthreads();
        float acc = 0.f;
#pragma unroll
        for (int k = 0; k < K; ++k) acc += xl[r * (K + 1) + k] * Wl[k * MT + j];
        const int row = base + r;
        if (row < n) {
            float v = acc;
            if (bias) v += bias[j];
            if (EPI >= 1) v = fmaxf(v, 0.f);
            out[(long)row * MFULL + j] = v;
        }
    }
}

// ---------------------------------------------------------------------------
// Per-node attention logits, fp16 xh input (__half2 loads)
// ---------------------------------------------------------------------------
template <int H, int C>
__global__ void gat_logits_kernel(const __half* __restrict__ xh, const float* __restrict__ a_s,
                                  const float* __restrict__ a_d, float* __restrict__ als,
                                  float* __restrict__ ald, int n) {
    int idx = blockIdx.x * blockDim.x + threadIdx.x;
    if (idx >= n * H) return;
    int node = idx / H, h = idx - node * H;
    const __half2* xp = (const __half2*)(xh + (long)node * NFEAT + h * C);  // h*C even
    float ss = 0.f, sd = 0.f;
#pragma unroll
    for (int c = 0; c < C / 2; ++c) {
        const float2 v = __half22float2(xp[c]);
        ss += v.x * a_s[h * C + 2 * c] + v.y * a_s[h * C + 2 * c + 1];
        sd += v.x * a_d[h * C + 2 * c] + v.y * a_d[h * C + 2 * c + 1];
    }
    als[idx] = ss;
    ald[idx] = sd;
}

// ---------------------------------------------------------------------------
// CSR build
// ---------------------------------------------------------------------------
__global__ void zero_int_kernel(int* __restrict__ p, int n) {
    int i = blockIdx.x * blockDim.x + threadIdx.x;
    if (i < n) p[i] = 0;
}

__global__ void hist_kernel(const int* __restrict__ ei, int E, int n, int* __restrict__ deg) {
    int e = blockIdx.x * blockDim.x + threadIdx.x;
    if (e >= E + n) return;
    int d = (e < E) ? ei[E + e] : (e - E);
    atomicAdd(&deg[d], 1);
}

__global__ void scanA_kernel(const int* __restrict__ deg, int n,
                             int* __restrict__ rowptr, int* __restrict__ bsum) {
    __shared__ int s[256];
    int t = threadIdx.x;
    int idx = blockIdx.x * 256 + t;
    s[t] = (idx < n) ? deg[idx] : 0;
    __syncthreads();
    for (int o = 1; o < 256; o <<= 1) {
        int x = (t >= o) ? s[t - o] : 0;
        __syncthreads();
        s[t] += x;
        __syncthreads();
    }
    if (idx < n) rowptr[idx + 1] = s[t];
    if (t == 255) bsum[blockIdx.x] = s[255];
}

__global__ void scanB_kernel(int* __restrict__ bsum, int nb) {
    __shared__ int s[256];
    int t = threadIdx.x;
    s[t] = (t < nb) ? bsum[t] : 0;
    __syncthreads();
    for (int o = 1; o < 256; o <<= 1) {
        int x = (t >= o) ? s[t - o] : 0;
        __syncthreads();
        s[t] += x;
        __syncthreads();
    }
    if (t < nb) bsum[t] = s[t];
}

__global__ void scanC_kernel(const int* __restrict__ deg, int n, int* __restrict__ rowptr,
                             const int* __restrict__ bsum, int* __restrict__ cursor) {
    int idx = blockIdx.x * 256 + threadIdx.x;
    if (idx >= n) return;
    int off = (blockIdx.x > 0) ? bsum[blockIdx.x - 1] : 0;
    int val = rowptr[idx + 1] + off;
    rowptr[idx + 1] = val;
    cursor[idx] = val - deg[idx];
    if (idx == 0) rowptr[0] = 0;
}

__global__ void scatter_kernel(const int* __restrict__ ei, int E, int n,
                               int* __restrict__ cursor, int* __restrict__ csr_src) {
    int e = blockIdx.x * blockDim.x + threadIdx.x;
    if (e >= E + n) return;
    int s, d;
    if (e < E) { s = ei[e]; d = ei[E + e]; } else { s = e - E; d = s; }
    int pos = atomicAdd(&cursor[d], 1);
    csr_src[pos] = s;
}

// ---------------------------------------------------------------------------
// Fused gather v4: fp16 xh. Lane covers features {2*lane, 2*lane+1} -> ONE
// 4-byte __half2 load per edge per lane (256B/wave = 2 cache lines vs 4 for
// fp32 — the gather was measured traffic-bound at FETCH=207MB, so halving
// bytes/edge is the lever). Both features share one head (head = lane>>4 for
// H=4) -> one LDS weight read + one den accumulator. Batch phase computes
// per-edge head weights into LDS; t-loop unrolled x4. No max-subtraction
// (the max cancels exactly in the softmax ratio; logits are exp-safe).
// ---------------------------------------------------------------------------
template <int H>
__launch_bounds__(256)
__global__ void gat_gather_kernel(const int* __restrict__ rowptr, const int* __restrict__ csr_src,
                                  const __half* __restrict__ xh, const float* __restrict__ als,
                                  const float* __restrict__ ald, const float* __restrict__ bias,
                                  const float* __restrict__ g, const float* __restrict__ be,
                                  const float* __restrict__ post, float* __restrict__ hout, int n) {
    __shared__ int   slds[4][64];
    __shared__ float wlds[4][64][H];
    const __half2* __restrict__ x2 = (const __half2*)xh;   // 64 half2 per row
    const int lane = threadIdx.x & 63;
    const int wid  = threadIdx.x >> 6;
    const int d = blockIdx.x * 4 + wid;
    if (d >= n) return;
    const int c0 = lane << 1;                       // features c0, c0+1 (same head)
    const int hh = (H == 4) ? (lane >> 4) : 0;
    float4 adv;
    if (H == 4) adv = *(const float4*)&ald[d * 4];
    else        adv.x = ald[d];
    const int rs = rowptr[d], re = rowptr[d + 1];   // deg >= 1 (self-loop)
    float den = 0.f, acc0 = 0.f, acc1 = 0.f;
    for (int base = rs; base < re; base += 64) {
        // ---- batch phase: lane's own edge -> head weights into LDS ----
        const bool valid = (base + lane) < re;
        int sv = 0;
        if (valid) sv = csr_src[base + lane];
        if (H == 4) {
            const float4 a = *(const float4*)&als[sv * 4];
            float l0 = a.x + adv.x, l1 = a.y + adv.y, l2 = a.z + adv.z, l3 = a.w + adv.w;
            l0 = l0 > 0.f ? l0 : 0.2f * l0;
            l1 = l1 > 0.f ? l1 : 0.2f * l1;
            l2 = l2 > 0.f ? l2 : 0.2f * l2;
            l3 = l3 > 0.f ? l3 : 0.2f * l3;
            float4 wv;
            wv.x = valid ? __expf(l0) : 0.f;
            wv.y = valid ? __expf(l1) : 0.f;
            wv.z = valid ? __expf(l2) : 0.f;
            wv.w = valid ? __expf(l3) : 0.f;
            slds[wid][lane] = sv;
            *(float4*)&wlds[wid][lane][0] = wv;
        } else {
            float l = als[sv] + adv.x;
            l = l > 0.f ? l : 0.2f * l;
            slds[wid][lane] = sv;
            wlds[wid][lane][0] = valid ? __expf(l) : 0.f;
        }
        const int cnt = min(64, re - base);
        const int cnt4 = (cnt + 3) & ~3;            // pad slots carry w=0, sv=0
        for (int t = 0; t < cnt4; t += 4) {
            const int s0 = slds[wid][t + 0];
            const int s1 = slds[wid][t + 1];
            const int s2 = slds[wid][t + 2];
            const int s3 = slds[wid][t + 3];
            const float w0 = wlds[wid][t + 0][hh];
            const float w1 = wlds[wid][t + 1][hh];
            const float w2 = wlds[wid][t + 2][hh];
            const float w3 = wlds[wid][t + 3][hh];
            const float2 x0 = __half22float2(x2[(long)s0 * 64 + lane]);
            const float2 x1 = __half22float2(x2[(long)s1 * 64 + lane]);
            const float2 x2v = __half22float2(x2[(long)s2 * 64 + lane]);
            const float2 x3 = __half22float2(x2[(long)s3 * 64 + lane]);
            den += (w0 + w1) + (w2 + w3);
            acc0 = fmaf(w0, x0.x, acc0);  acc1 = fmaf(w0, x0.y, acc1);
            acc0 = fmaf(w1, x1.x, acc0);  acc1 = fmaf(w1, x1.y, acc1);
            acc0 = fmaf(w2, x2v.x, acc0); acc1 = fmaf(w2, x2v.y, acc1);
            acc0 = fmaf(w3, x3.x, acc0);  acc1 = fmaf(w3, x3.y, acc1);
        }
    }
    const float2 bv = *(const float2*)&bias[c0];
    const float2 gv = *(const float2*)&g[c0];
    const float2 ev = *(const float2*)&be[c0];
    const float rden = 1.f / den;
    float v0 = (acc0 * rden + bv.x) * (gv.x * BN_RSQ) + ev.x;
    float v1 = (acc1 * rden + bv.y) * (gv.y * BN_RSQ) + ev.y;
    v0 = v0 > 0.f ? v0 : expm1f(v0);                // elu
    v1 = v1 > 0.f ? v1 : expm1f(v1);
    if (post) { const float2 pv = *(const float2*)&post[c0]; v0 *= pv.x; v1 *= pv.y; }
    float2 o; o.x = v0; o.y = v1;
    *(float2*)&hout[(long)d * NFEAT + c0] = o;
}

// ---------------------------------------------------------------------------
template <int H>
static void run_gat_layer(const float* hin, __half* xh, float* als, float* ald,
                          const int* rowptr, const int* csr_src, int n,
                          const float* W, const float* as_, const float* ad_, const float* b,
                          const float* g, const float* be, const float* post, float* hout,
                          hipStream_t stream) {
    constexpr int C = NFEAT / H;
    linear8_kernel<128, 1><<<(n + 63) / 64, 256, 0, stream>>>(hin, W, nullptr, (void*)xh, n);
    gat_logits_kernel<H, C><<<(n * H + 255) / 256, 256, 0, stream>>>(xh, as_, ad_, als, ald, n);
    gat_gather_kernel<H><<<(n + 3) / 4, 256, 0, stream>>>(rowptr, csr_src, xh, als, ald,
                                                          b, g, be, post, hout, n);
}

extern "C" void kernel_launch(void* const* d_in, const int* in_sizes, int n_in,
                              void* d_out, int out_size, void* d_ws, size_t ws_size,
                              hipStream_t stream) {
    const float* x   = (const float*)d_in[0];
    const int*   ei  = (const int*)d_in[1];
    const float* Wp  = (const float*)d_in[2];
    const float* bp  = (const float*)d_in[3];
    const float* W0  = (const float*)d_in[4];
    const float* as0 = (const float*)d_in[5];
    const float* ad0 = (const float*)d_in[6];
    const float* b0  = (const float*)d_in[7];
    const float* g0  = (const float*)d_in[8];
    const float* be0 = (const float*)d_in[9];
    const float* W1  = (const float*)d_in[10];
    const float* as1 = (const float*)d_in[11];
    const float* ad1 = (const float*)d_in[12];
    const float* b1  = (const float*)d_in[13];
    const float* g1  = (const float*)d_in[14];
    const float* be1 = (const float*)d_in[15];
    const float* W2  = (const float*)d_in[16];
    const float* as2 = (const float*)d_in[17];
    const float* ad2 = (const float*)d_in[18];
    const float* b2  = (const float*)d_in[19];
    const float* g2  = (const float*)d_in[20];
    const float* be2 = (const float*)d_in[21];
    const float* fi  = (const float*)d_in[22];
    const float* Wc1 = (const float*)d_in[23];
    const float* bc1 = (const float*)d_in[24];
    const float* gc  = (const float*)d_in[25];
    const float* bec = (const float*)d_in[26];
    const float* Wc2 = (const float*)d_in[27];
    const float* bc2 = (const float*)d_in[28];
    const float* Wc3 = (const float*)d_in[29];
    const float* bc3 = (const float*)d_in[30];

    const int n  = in_sizes[0] / INF;      // 50000
    const int E  = in_sizes[1] / 2;        // 800000
    const int E2 = E + n;                  // + self-loops
    const int NB = (n + 255) / 256;        // scan blocks (<=256)

    float* ws   = (float*)d_ws;
    float* h    = ws;                          // n*128 fp32
    __half* xh  = (__half*)(h + (long)n * NFEAT);  // n*128 fp16 (uses half the old slot)
    float* als  = h + (long)n * NFEAT * 2;     // n*4  (same offsets as before)
    float* ald  = als + (long)n * 4;           // n*4
    int* deg     = (int*)(ald + (long)n * 4);  // n
    int* rowptr  = deg + n;                    // n+1
    int* cursor  = rowptr + (n + 1);           // n
    int* csr_src = cursor + n;                 // E2
    int* bsum    = csr_src + (long)E2;         // NB

    // CSR build (by dst)
    zero_int_kernel<<<NB, 256, 0, stream>>>(deg, n);
    hist_kernel<<<(E2 + 255) / 256, 256, 0, stream>>>(ei, E, n, deg);
    scanA_kernel<<<NB, 256, 0, stream>>>(deg, n, rowptr, bsum);
    scanB_kernel<<<1, 256, 0, stream>>>(bsum, NB);
    scanC_kernel<<<NB, 256, 0, stream>>>(deg, n, rowptr, bsum, cursor);
    scatter_kernel<<<(E2 + 255) / 256, 256, 0, stream>>>(ei, E, n, cursor, csr_src);

    // projection: h = x @ Wp + bp (fp32 out)
    linear8_kernel<64, 0><<<(n + 63) / 64, 256, 0, stream>>>(x, Wp, bp, (void*)h, n);

    // GAT layers (h -> h across kernels; stream-ordered; xh is fp16)
    run_gat_layer<4>(h, xh, als, ald, rowptr, csr_src, n, W0, as0, ad0, b0, g0, be0, nullptr, h, stream);
    run_gat_layer<4>(h, xh, als, ald, rowptr, csr_src, n, W1, as1, ad1, b1, g1, be1, nullptr, h, stream);
    run_gat_layer<1>(h, xh, als, ald, rowptr, csr_src, n, W2, as2, ad2, b2, g2, be2, fi, h, stream);

    // classifier: c1 = bn(relu(h@Wc1+bc1)) -> c1buf ; c2 = relu(c1@Wc2+bc2) -> h ; out
    float* c1buf = h + (long)n * NFEAT;        // reuse xh slot as fp32 n*64 (fits: slot is n*128 fp16 = n*64 fp32)
    {
        dim3 grid((n + 63) / 64, 1);
        linear4_kernel<128, 64, 2><<<grid, 256, 0, stream>>>(h, Wc1, bc1, gc, bec, c1buf, n);
    }
    linear_kernel<64, 32, 32, 1, 8><<<(n + 63) / 64, 256, 0, stream>>>(c1buf, Wc2, bc2, h, n);
    linear_kernel<32, 2, 2, 0, 2><<<(n + 255) / 256, 256, 0, stream>>>(h, Wc3, bc3, (float*)d_out, n);
}